// Round 6
// baseline (357.131 us; speedup 1.0000x reference)
//
#include <hip/hip_runtime.h>
#include <hip/hip_bf16.h>

// ModulatedConv2D (B=16, CIN=COUT=512, H=W=32, K=3) — bf16-split implicit GEMM v3.
//
// v3 structural changes vs v2 (which ran 215.7 µs, MfmaUtil 48.6, conflicts 1.9e7):
//  * W operand bypasses LDS: precomputed fragment-linear WT3 [cb][step][half][mi][hilo][lane][8]
//    -> per-wave 8 perfectly-coalesced b128 global loads / step, register double-buffered.
//  * 2-phase pipeline: stage(step+1) + prefetch W(step+1) issued BEFORE step's MFMA,
//    ONE __syncthreads per step; its vmcnt(0) drain is covered by the MFMA phase.
//  * I halo buffer chunk-XOR-swizzled (phys chunk = c16 ^ ((xp>>1)&3)) at isplit-write;
//    conv ds_read XORs the same sigma -> all 8 bank slots covered (2-way = free).
//  * XCD-contiguous block swizzle (512 blocks: each XCD sees one coutblk's W = 2.36MB, L2-fit).
//  * wsum fused into wsplit (atomicAdd into memset-zeroed S).
//
// ws: style 32KB | S 6KB | dn | @64KB WT3 9.44MB | Ihi 18.9MB | Ilo 18.9MB  (~47.3MB)

typedef short short8 __attribute__((ext_vector_type(8)));
typedef float f32x4 __attribute__((ext_vector_type(4)));

__device__ __forceinline__ ushort bf16_rtne(float f) {
    unsigned u = __float_as_uint(f);
    unsigned r = u + 0x7fffu + ((u >> 16) & 1u);
    return (ushort)(r >> 16);
}
__device__ __forceinline__ float bf16_up(ushort h) {
    return __uint_as_float(((unsigned)h) << 16);
}
__device__ __forceinline__ void gld16(const void* g, void* l) {
    __builtin_amdgcn_global_load_lds(
        (const __attribute__((address_space(1))) unsigned int*)g,
        (__attribute__((address_space(3))) unsigned int*)l, 16, 0, 0);
}

__global__ __launch_bounds__(256) void style_kernel(const float* __restrict__ wl,
                                                    const float* __restrict__ dk,
                                                    const float* __restrict__ bias,
                                                    float* __restrict__ style) {
    __shared__ float wsh[512];
    __shared__ float red[4][64];
    const int b = blockIdx.y, c0 = blockIdx.x * 64, t = threadIdx.x;
    for (int i = t; i < 512; i += 256) wsh[i] = wl[b * 512 + i];
    __syncthreads();
    const int c = c0 + (t & 63), kq = (t >> 6) * 128;
    float acc = 0.f;
    #pragma unroll 8
    for (int k = 0; k < 128; ++k)
        acc = fmaf(wsh[kq + k], dk[(size_t)(kq + k) * 512 + c], acc);
    red[t >> 6][t & 63] = acc;
    __syncthreads();
    if (t < 64)
        style[b * 512 + c0 + t] =
            red[0][t] + red[1][t] + red[2][t] + red[3][t] + bias[c0 + t];
}

__global__ void denom_kernel(const float* __restrict__ S,
                             const float* __restrict__ style,
                             float* __restrict__ dn) {
    int bid = blockIdx.x;            // b*3 + kh
    int b = bid / 3, kh = bid % 3;
    int lane = threadIdx.x;
    float acc = 0.f;
    for (int c = lane; c < 512; c += 64) {
        float s = style[b * 512 + c];
        acc = fmaf(S[kh * 512 + c], s * s, acc);
    }
    #pragma unroll
    for (int off = 32; off; off >>= 1) acc += __shfl_down(acc, off);
    if (lane == 0) dn[bid] = rsqrtf(acc);
}

// conv_w [4608][512] f32 -> fragment-linear split WT3; fused S accumulation.
__global__ __launch_bounds__(256) void wsplit_kernel(const float* __restrict__ cw,
                                                     ushort* __restrict__ wt3,
                                                     float* __restrict__ S) {
    __shared__ ushort hs[64][72];
    __shared__ ushort ls[64][72];
    int t = threadIdx.x;
    int k0 = blockIdx.x * 64, c0 = blockIdx.y * 64;
    int col = t & 63;
    int rq = t >> 6;
    const int khw = k0 >> 9;
    const int kh = khw >= 6 ? 2 : (khw >= 3 ? 1 : 0);
    #pragma unroll
    for (int i = 0; i < 16; ++i) {
        int kr = rq * 16 + i;
        float v = cw[(size_t)(k0 + kr) * 512 + c0 + col];
        ushort hh = bf16_rtne(v);
        ushort ll = bf16_rtne(v - bf16_up(hh));
        hs[col][kr] = hh;            // transpose on write
        ls[col][kr] = ll;
        // fused wsum: reduce v^2 over the 64 cout lanes of this wave
        float sq = v * v;
        #pragma unroll
        for (int off = 32; off; off >>= 1) sq += __shfl_down(sq, off);
        if ((t & 63) == 0)
            atomicAdd(&S[kh * 512 + ((k0 & 511) + kr)], sq);
    }
    __syncthreads();
    int r = t >> 2, kq = (t & 3) << 4;        // kq in {0,16,32,48}
    int cout = c0 + r;
    int k = k0 + kq;
    // WT3 idx: ((cb*144+step)*2 + half)*4096 + (mi*2+hilo)*512 + (c16*16 + rl)*8
    size_t o = ((size_t)((cout >> 7) * 144 + (k >> 5)) * 2 + ((cout >> 6) & 1)) * 4096
             + (size_t)((cout >> 4) & 3) * 1024
             + (size_t)(((k >> 3) & 3) * 16 + (cout & 15)) * 8;
    *(uint4*)&wt3[o]       = *(const uint4*)&hs[r][kq];       // hi, chunk c16
    *(uint4*)&wt3[o + 128] = *(const uint4*)&hs[r][kq + 8];   // hi, chunk c16+1
    *(uint4*)&wt3[o + 512] = *(const uint4*)&ls[r][kq];       // lo
    *(uint4*)&wt3[o + 640] = *(const uint4*)&ls[r][kq + 8];
}

// img -> zero-halo split (img*style), chunk-swizzled: phys chunk = c16 ^ ((xp>>1)&3)
__global__ __launch_bounds__(256) void isplit_kernel(const float* __restrict__ img,
                                                     const float* __restrict__ style,
                                                     ushort* __restrict__ ihi,
                                                     ushort* __restrict__ ilo) {
    const int b = blockIdx.y, yp = blockIdx.x, t = threadIdx.x;
    const size_t rowbase = (size_t)(b * 34 + yp) * 34 * 512;
    uint4 z = {0u, 0u, 0u, 0u};
    if (yp == 0 || yp == 33) {
        for (int i = t; i < 2176; i += 256) {
            ((uint4*)(ihi + rowbase))[i] = z;
            ((uint4*)(ilo + rowbase))[i] = z;
        }
        return;
    }
    if (t < 64) {                        // zero xp=0 and xp=33 columns
        ((uint4*)(ihi + rowbase))[t] = z;
        ((uint4*)(ilo + rowbase))[t] = z;
        ((uint4*)(ihi + rowbase + 33 * 512))[t] = z;
        ((uint4*)(ilo + rowbase + 33 * 512))[t] = z;
    }
    const int y = yp - 1;
    __shared__ float buf[64][33];
    const int ci = t >> 5, x = t & 31;       // load role
    const int xo = t >> 3, cs = (t & 7) * 8; // store role
    const int xp = xo + 1;
    const int sig = (xp >> 1) & 3;
    // physical store offset for this thread's 8-elem chunk
    const size_t o_sw = rowbase + (size_t)xp * 512 + (cs & 32)
                      + (size_t)((((cs >> 3) & 3) ^ sig) << 3);
    for (int c0 = 0; c0 < 512; c0 += 64) {
        __syncthreads();
        #pragma unroll
        for (int i = 0; i < 8; ++i) {
            int cin = c0 + ci + i * 8;
            float v = img[((size_t)(b * 512 + cin) * 32 + y) * 32 + x] *
                      style[b * 512 + cin];
            buf[ci + i * 8][x] = v;
        }
        __syncthreads();
        union { ushort u[8]; uint4 v; } hb, lb;
        #pragma unroll
        for (int i = 0; i < 8; ++i) {
            float v = buf[cs + i][xo];
            ushort hh = bf16_rtne(v);
            hb.u[i] = hh;
            lb.u[i] = bf16_rtne(v - bf16_up(hh));
        }
        *(uint4*)&ihi[o_sw + c0] = hb.v;
        *(uint4*)&ilo[o_sw + c0] = lb.v;
    }
}

// ---- main GEMM: 128 cout x 128 pix block, BK=32, 4 waves, 2-phase pipeline ----
__global__ __launch_bounds__(256, 2) void conv_gemm(
    const ushort* __restrict__ wt3,    // fragment-linear W (hi+lo)
    const ushort* __restrict__ ihh,    // swizzled halo hi [16][34][34][512]
    const ushort* __restrict__ ihl,    // swizzled halo lo
    const float*  __restrict__ dn,     // [16][3]
    float* __restrict__ out)           // [16][512][32][32]
{
    __shared__ ushort Ih[2][128][32];
    __shared__ ushort Io[2][128][32];

    const int tid  = threadIdx.x;
    const int lane = tid & 63;
    const int wid  = tid >> 6;

    // XCD-contiguous swizzle: each XCD gets 64 consecutive swz -> one coutblk's W slice
    const int g   = blockIdx.x;                // 0..511
    const int swz = ((g & 7) << 6) | (g >> 3);
    const int coutblk = swz >> 7;              // 0..3
    const int pixblk  = swz & 127;             // 0..127
    const int b        = pixblk >> 3;
    const int pix_base = (pixblk & 7) << 7;

    const int wr = (wid >> 1) * 64;
    const int wc = (wid & 1) * 64;
    const int rl  = lane & 15;
    const int kgB = (lane >> 4) << 3;          // logical k-chunk elem offset

    // ---- I staging geometry: wave stages rows [wid*32, +32) of both tiles ----
    const int r0 = wid << 5;
    const int rA = r0 + (lane >> 2);
    const int rB = rA + 16;
    const int ck = (lane & 3) << 3;
    const size_t ibase = (size_t)b * 34 * 34 * 512;
    const int gpA = pix_base + rA, gpB = pix_base + rB;
    const size_t pAoff = ibase + (size_t)((gpA >> 5) * 34 + (gpA & 31)) * 512 + ck;
    const size_t pBoff = ibase + (size_t)((gpB >> 5) * 34 + (gpB & 31)) * 512 + ck;

    // ---- W base: fragment-linear, per-lane ----
    const int half = wid >> 1;
    const ushort* wpBase = wt3 + (size_t)coutblk * 1179648 + (size_t)half * 4096 + lane * 8;

    const float d0 = dn[b * 3 + 0];
    const float d1 = dn[b * 3 + 1];
    const float d2 = dn[b * 3 + 2];

    f32x4 acc[4][4];
    #pragma unroll
    for (int i = 0; i < 4; ++i)
        #pragma unroll
        for (int j = 0; j < 4; ++j) acc[i][j] = (f32x4)0.f;

    short8 wRegA[8], wRegB[8];

    // ---- prologue: stage step 0 into buf0, load W[0] into wRegA ----
    gld16(ihh + pAoff, &Ih[0][r0][0]);
    gld16(ihh + pBoff, &Ih[0][r0 + 16][0]);
    gld16(ihl + pAoff, &Io[0][r0][0]);
    gld16(ihl + pBoff, &Io[0][r0 + 16][0]);
    #pragma unroll
    for (int j = 0; j < 8; ++j) wRegA[j] = *(const short8*)(wpBase + j * 512);
    __syncthreads();   // drains gld_lds + W loads

#define CONV_BODY(STEP, CUR, WUSE, WPRE)                                          \
    {                                                                             \
        const int step = (STEP);                                                  \
        const int khw  = step >> 4;                                               \
        const int kh   = khw >= 6 ? 2 : (khw >= 3 ? 1 : 0);                       \
        const int kw   = khw - kh * 3;                                            \
        if (step < 143) {                                                         \
            const int s1   = step + 1;                                            \
            const int khw1 = s1 >> 4;                                             \
            const int kh1  = khw1 >= 6 ? 2 : (khw1 >= 3 ? 1 : 0);                 \
            const int kw1  = khw1 - kh1 * 3;                                      \
            const int soff1 = (kh1 * 34 + kw1) * 512 + ((s1 << 5) & 511);         \
            gld16(ihh + pAoff + soff1, &Ih[(CUR) ^ 1][r0][0]);                    \
            gld16(ihh + pBoff + soff1, &Ih[(CUR) ^ 1][r0 + 16][0]);               \
            gld16(ihl + pAoff + soff1, &Io[(CUR) ^ 1][r0][0]);                    \
            gld16(ihl + pBoff + soff1, &Io[(CUR) ^ 1][r0 + 16][0]);               \
            const ushort* wsrc = wpBase + (size_t)s1 * 8192;                      \
            _Pragma("unroll")                                                     \
            for (int j = 0; j < 8; ++j) WPRE[j] = *(const short8*)(wsrc + j * 512);\
        }                                                                         \
        const int sig = (((rl + kw) >> 1) & 3) << 3;                              \
        const int colr = kgB ^ sig;                                               \
        short8 ia[4], il[4];                                                      \
        _Pragma("unroll")                                                         \
        for (int ni = 0; ni < 4; ++ni) {                                          \
            const int row = wc + ni * 16 + rl;                                    \
            ia[ni] = *(const short8*)&Ih[CUR][row][colr];                         \
            il[ni] = *(const short8*)&Io[CUR][row][colr];                         \
        }                                                                         \
        _Pragma("unroll")                                                         \
        for (int mi = 0; mi < 4; ++mi) {                                          \
            _Pragma("unroll")                                                     \
            for (int ni = 0; ni < 4; ++ni) {                                      \
                acc[mi][ni] = __builtin_amdgcn_mfma_f32_16x16x32_bf16(            \
                    WUSE[mi * 2 + 0], ia[ni], acc[mi][ni], 0, 0, 0);              \
                acc[mi][ni] = __builtin_amdgcn_mfma_f32_16x16x32_bf16(            \
                    WUSE[mi * 2 + 0], il[ni], acc[mi][ni], 0, 0, 0);              \
                acc[mi][ni] = __builtin_amdgcn_mfma_f32_16x16x32_bf16(            \
                    WUSE[mi * 2 + 1], ia[ni], acc[mi][ni], 0, 0, 0);              \
            }                                                                     \
        }                                                                         \
        if (step == 47 || step == 95) {                                           \
            const float rr = (step == 47) ? (d0 / d1) : (d1 / d2);                \
            _Pragma("unroll")                                                     \
            for (int mi = 0; mi < 4; ++mi)                                        \
                _Pragma("unroll")                                                 \
                for (int ni = 0; ni < 4; ++ni) acc[mi][ni] *= rr;                 \
        }                                                                         \
        __syncthreads();                                                          \
    }

    for (int it = 0; it < 72; ++it) {
        CONV_BODY(2 * it,     0, wRegA, wRegB)
        CONV_BODY(2 * it + 1, 1, wRegB, wRegA)
    }
#undef CONV_BODY

    // ---- epilogue: x d2, store (col=lane&15 -> pixel, row=(lane>>4)*4+reg -> cout) ----
    const int cout_base = coutblk << 7;
    #pragma unroll
    for (int mi = 0; mi < 4; ++mi) {
        const int crow = cout_base + wr + mi * 16 + ((lane >> 4) << 2);
        #pragma unroll
        for (int ni = 0; ni < 4; ++ni) {
            const int ccol = pix_base + wc + ni * 16 + (lane & 15);
            float* op = out + ((size_t)(b << 9) + crow) * 1024 + ccol;
            f32x4 c = acc[mi][ni];
            #pragma unroll
            for (int r = 0; r < 4; ++r)
                op[(size_t)r * 1024] = c[r] * d2;
        }
    }
}

extern "C" void kernel_launch(void* const* d_in, const int* in_sizes, int n_in,
                              void* d_out, int out_size, void* d_ws, size_t ws_size,
                              hipStream_t stream) {
    const float* img  = (const float*)d_in[0];   // [16][512][32][32]
    const float* wl   = (const float*)d_in[1];   // [16][512]
    const float* dk   = (const float*)d_in[2];   // [512][512]
    const float* bias = (const float*)d_in[3];   // [512]
    const float* cw   = (const float*)d_in[4];   // [3][3][512][512]
    float* out = (float*)d_out;

    float* style = (float*)d_ws;                           // 8192 f32
    float* S     = style + 8192;                           // 1536 f32
    float* dn    = S + 1536;                               // 48 f32
    ushort* wt3  = (ushort*)((char*)d_ws + 65536);         // 4*144*8192 elems
    ushort* ihi  = wt3 + (size_t)4 * 144 * 8192;           // [16][34][34][512]
    ushort* ilo  = ihi + (size_t)16 * 34 * 34 * 512;

    hipMemsetAsync(S, 0, 1536 * sizeof(float), stream);
    style_kernel<<<dim3(8, 16), 256, 0, stream>>>(wl, dk, bias, style);
    wsplit_kernel<<<dim3(72, 8), 256, 0, stream>>>(cw, wt3, S);
    denom_kernel<<<48, 64, 0, stream>>>(S, style, dn);
    isplit_kernel<<<dim3(34, 16), 256, 0, stream>>>(img, style, ihi, ilo);

    conv_gemm<<<512, 256, 0, stream>>>(wt3, ihi, ilo, dn, out);
}

// Round 7
// 329.117 us; speedup vs baseline: 1.0851x; 1.0851x over previous
//
#include <hip/hip_runtime.h>
#include <hip/hip_bf16.h>

// ModulatedConv2D (B=16, CIN=COUT=512, H=W=32, K=3) — bf16-split implicit GEMM v4.
//
// v4 vs v3 (260 µs, FETCH 611 MB, HBM-bound): kill the 9x image re-read.
//   * Loop order: cin-chunk (16 x 32) OUTER, (kh,kw) shifts INNER.
//   * Stage 6 halo rows x 34 xp x 32 cin ONCE per chunk (dbuf LDS, 57 KB);
//     all 9 shifts read from LDS -> per-block I-traffic 2.36 MB -> 418 KB.
//   * [224][32] LDS tile: slot = (4*rl + kchunk) mod 8 is uniformly balanced ->
//     conflict-free WITHOUT swizzle (isplit swizzle removed).
//   * One barrier per chunk (16 total); 432-MFMA unbroken phases; W frags
//     register-double-buffered from fragment-linear WT3 (unchanged).
//   * denom folded exactly via rescale at every kh transition (r01,r12,r20).
//
// ws: style 32KB | S | dn | @64KB WT3 9.44MB | Ihi 18.9MB | Ilo 18.9MB (~47.3MB)

typedef short short8 __attribute__((ext_vector_type(8)));
typedef float f32x4 __attribute__((ext_vector_type(4)));

__device__ __forceinline__ ushort bf16_rtne(float f) {
    unsigned u = __float_as_uint(f);
    unsigned r = u + 0x7fffu + ((u >> 16) & 1u);
    return (ushort)(r >> 16);
}
__device__ __forceinline__ float bf16_up(ushort h) {
    return __uint_as_float(((unsigned)h) << 16);
}
__device__ __forceinline__ void gld16(const void* g, void* l) {
    __builtin_amdgcn_global_load_lds(
        (const __attribute__((address_space(1))) unsigned int*)g,
        (__attribute__((address_space(3))) unsigned int*)l, 16, 0, 0);
}

__global__ __launch_bounds__(256) void style_kernel(const float* __restrict__ wl,
                                                    const float* __restrict__ dk,
                                                    const float* __restrict__ bias,
                                                    float* __restrict__ style) {
    __shared__ float wsh[512];
    __shared__ float red[4][64];
    const int b = blockIdx.y, c0 = blockIdx.x * 64, t = threadIdx.x;
    for (int i = t; i < 512; i += 256) wsh[i] = wl[b * 512 + i];
    __syncthreads();
    const int c = c0 + (t & 63), kq = (t >> 6) * 128;
    float acc = 0.f;
    #pragma unroll 8
    for (int k = 0; k < 128; ++k)
        acc = fmaf(wsh[kq + k], dk[(size_t)(kq + k) * 512 + c], acc);
    red[t >> 6][t & 63] = acc;
    __syncthreads();
    if (t < 64)
        style[b * 512 + c0 + t] =
            red[0][t] + red[1][t] + red[2][t] + red[3][t] + bias[c0 + t];
}

__global__ void denom_kernel(const float* __restrict__ S,
                             const float* __restrict__ style,
                             float* __restrict__ dn) {
    int bid = blockIdx.x;            // b*3 + kh
    int b = bid / 3, kh = bid % 3;
    int lane = threadIdx.x;
    float acc = 0.f;
    for (int c = lane; c < 512; c += 64) {
        float s = style[b * 512 + c];
        acc = fmaf(S[kh * 512 + c], s * s, acc);
    }
    #pragma unroll
    for (int off = 32; off; off >>= 1) acc += __shfl_down(acc, off);
    if (lane == 0) dn[bid] = rsqrtf(acc);
}

// conv_w [4608][512] f32 -> fragment-linear split WT3; fused S accumulation.
__global__ __launch_bounds__(256) void wsplit_kernel(const float* __restrict__ cw,
                                                     ushort* __restrict__ wt3,
                                                     float* __restrict__ S) {
    __shared__ ushort hs[64][72];
    __shared__ ushort ls[64][72];
    int t = threadIdx.x;
    int k0 = blockIdx.x * 64, c0 = blockIdx.y * 64;
    int col = t & 63;
    int rq = t >> 6;
    const int khw = k0 >> 9;
    const int kh = khw >= 6 ? 2 : (khw >= 3 ? 1 : 0);
    #pragma unroll
    for (int i = 0; i < 16; ++i) {
        int kr = rq * 16 + i;
        float v = cw[(size_t)(k0 + kr) * 512 + c0 + col];
        ushort hh = bf16_rtne(v);
        ushort ll = bf16_rtne(v - bf16_up(hh));
        hs[col][kr] = hh;            // transpose on write
        ls[col][kr] = ll;
        float sq = v * v;
        #pragma unroll
        for (int off = 32; off; off >>= 1) sq += __shfl_down(sq, off);
        if ((t & 63) == 0)
            atomicAdd(&S[kh * 512 + ((k0 & 511) + kr)], sq);
    }
    __syncthreads();
    int r = t >> 2, kq = (t & 3) << 4;        // kq in {0,16,32,48}
    int cout = c0 + r;
    int k = k0 + kq;
    // WT3 idx: ((cb*144+step)*2 + half)*4096 + (mi*2+hilo)*512 + (c16*16 + rl)*8
    size_t o = ((size_t)((cout >> 7) * 144 + (k >> 5)) * 2 + ((cout >> 6) & 1)) * 4096
             + (size_t)((cout >> 4) & 3) * 1024
             + (size_t)(((k >> 3) & 3) * 16 + (cout & 15)) * 8;
    *(uint4*)&wt3[o]       = *(const uint4*)&hs[r][kq];       // hi, chunk c16
    *(uint4*)&wt3[o + 128] = *(const uint4*)&hs[r][kq + 8];   // hi, chunk c16+1
    *(uint4*)&wt3[o + 512] = *(const uint4*)&ls[r][kq];       // lo
    *(uint4*)&wt3[o + 640] = *(const uint4*)&ls[r][kq + 8];
}

// img -> zero-halo split (img*style), NATURAL layout [16][34][34][512]
__global__ __launch_bounds__(256) void isplit_kernel(const float* __restrict__ img,
                                                     const float* __restrict__ style,
                                                     ushort* __restrict__ ihi,
                                                     ushort* __restrict__ ilo) {
    const int b = blockIdx.y, yp = blockIdx.x, t = threadIdx.x;
    const size_t rowbase = (size_t)(b * 34 + yp) * 34 * 512;
    uint4 z = {0u, 0u, 0u, 0u};
    if (yp == 0 || yp == 33) {
        for (int i = t; i < 2176; i += 256) {
            ((uint4*)(ihi + rowbase))[i] = z;
            ((uint4*)(ilo + rowbase))[i] = z;
        }
        return;
    }
    if (t < 64) {                        // zero xp=0 and xp=33 columns
        ((uint4*)(ihi + rowbase))[t] = z;
        ((uint4*)(ilo + rowbase))[t] = z;
        ((uint4*)(ihi + rowbase + 33 * 512))[t] = z;
        ((uint4*)(ilo + rowbase + 33 * 512))[t] = z;
    }
    const int y = yp - 1;
    __shared__ float buf[64][33];
    const int ci = t >> 5, x = t & 31;       // load role
    const int xo = t >> 3, cs = (t & 7) * 8; // store role
    for (int c0 = 0; c0 < 512; c0 += 64) {
        __syncthreads();
        #pragma unroll
        for (int i = 0; i < 8; ++i) {
            int cin = c0 + ci + i * 8;
            float v = img[((size_t)(b * 512 + cin) * 32 + y) * 32 + x] *
                      style[b * 512 + cin];
            buf[ci + i * 8][x] = v;
        }
        __syncthreads();
        union { ushort u[8]; uint4 v; } hb, lb;
        #pragma unroll
        for (int i = 0; i < 8; ++i) {
            float v = buf[cs + i][xo];
            ushort hh = bf16_rtne(v);
            hb.u[i] = hh;
            lb.u[i] = bf16_rtne(v - bf16_up(hh));
        }
        size_t o = rowbase + (size_t)(xo + 1) * 512 + c0 + cs;
        *(uint4*)&ihi[o] = hb.v;
        *(uint4*)&ilo[o] = lb.v;
    }
}

// ---- main GEMM: 128 cout x 128 pix block; cin-chunk outer, 9 shifts inner ----
__global__ __launch_bounds__(256, 2) void conv_gemm(
    const ushort* __restrict__ wt3,    // fragment-linear W (hi+lo)
    const ushort* __restrict__ ihh,    // halo hi [16][34][34][512]
    const ushort* __restrict__ ihl,    // halo lo
    const float*  __restrict__ dn,     // [16][3]
    float* __restrict__ out)           // [16][512][32][32]
{
    __shared__ ushort Hs[2][224][32];  // halo hi tile: rows r=(yr*36+xp), 32 cin
    __shared__ ushort Ls[2][224][32];  // halo lo tile

    const int tid  = threadIdx.x;
    const int lane = tid & 63;
    const int wid  = tid >> 6;

    // XCD-contiguous swizzle (512 blocks; each XCD's W slice = 2.36 MB, L2-fit)
    const int g   = blockIdx.x;
    const int swz = ((g & 7) << 6) | (g >> 3);
    const int coutblk = swz >> 7;              // 0..3
    const int pixblk  = swz & 127;             // 0..127
    const int b        = pixblk >> 3;
    const int pix_base = (pixblk & 7) << 7;
    const int Y0       = pix_base >> 5;        // first y-row of this block

    const int wr  = (wid >> 1) * 64;           // wave cout-offset
    const int wc  = (wid & 1) * 64;            // wave pix-offset
    const int rl  = lane & 15;
    const int kgB = (lane >> 4) << 3;

    const size_t ibase = (size_t)b * 34 * 34 * 512;
    const int half = wid >> 1;
    const ushort* wpBase = wt3 + (size_t)coutblk * 1179648 + (size_t)half * 4096 + lane * 8;

    const float d0 = dn[b * 3 + 0];
    const float d1 = dn[b * 3 + 1];
    const float d2 = dn[b * 3 + 2];
    const float r01 = d0 / d1, r12 = d1 / d2, r20 = d2 / d0;

    f32x4 acc[4][4];
    #pragma unroll
    for (int i = 0; i < 4; ++i)
        #pragma unroll
        for (int j = 0; j < 4; ++j) acc[i][j] = (f32x4)0.f;

    short8 wA[8], wB[8];

// stage halo chunk CEV (cin = CEV*32..+31) into buffer NB: 28 gld16 calls, 7/wave
#define STAGE(CEV, NB)                                                         \
    { _Pragma("unroll")                                                        \
      for (int kk = 0; kk < 7; ++kk) {                                         \
        const int kc = wid + kk * 4;                                           \
        const int tsel = kc & 1;                                               \
        const int rb = (kc >> 1) << 4;                                         \
        const int r  = rb + (lane >> 2);                                       \
        const int yr = r / 36, xp = r - yr * 36;                               \
        const int yp = min(Y0 + yr, 33), xpc = min(xp, 33);                    \
        const ushort* src = (tsel ? ihl : ihh) + ibase                         \
            + ((size_t)(yp * 34 + xpc) << 9) + ((CEV) << 5)                    \
            + ((lane & 3) << 3);                                               \
        ushort* dst = tsel ? &Ls[NB][rb][0] : &Hs[NB][rb][0];                  \
        gld16(src, dst);                                                       \
      } }

#define RESCALE(RR)                                                            \
    { _Pragma("unroll")                                                        \
      for (int mi = 0; mi < 4; ++mi)                                           \
        _Pragma("unroll")                                                      \
        for (int ni = 0; ni < 4; ++ni) acc[mi][ni] *= (RR); }

// one (kh,kw) k-step: prefetch next W frags, 8 ds_read_b128, 48 MFMA
#define STEP(S9, CEV, WUSE, WPRE, BUF)                                         \
    {                                                                          \
        const int kh = (S9) / 3, kw = (S9) % 3;                                \
        const int ns = ((S9) == 8) ? 0 : (S9) + 1;                             \
        const int nc = ((S9) == 8) ? (CEV) + 1 : (CEV);                        \
        if (nc < 16) {                                                         \
            const ushort* wsrc = wpBase + (size_t)(ns * 16 + nc) * 8192;       \
            _Pragma("unroll")                                                  \
            for (int j = 0; j < 8; ++j)                                        \
                WPRE[j] = *(const short8*)(wsrc + j * 512);                    \
        }                                                                      \
        short8 ia[4], il[4];                                                   \
        _Pragma("unroll")                                                      \
        for (int ni = 0; ni < 4; ++ni) {                                       \
            const int R0 = ((wc >> 5) + (ni >> 1) + kh) * 36                   \
                         + (ni & 1) * 16 + kw;                                 \
            ia[ni] = *(const short8*)&Hs[BUF][R0 + rl][kgB];                   \
            il[ni] = *(const short8*)&Ls[BUF][R0 + rl][kgB];                   \
        }                                                                      \
        _Pragma("unroll")                                                      \
        for (int mi = 0; mi < 4; ++mi) {                                       \
            _Pragma("unroll")                                                  \
            for (int ni = 0; ni < 4; ++ni) {                                   \
                acc[mi][ni] = __builtin_amdgcn_mfma_f32_16x16x32_bf16(         \
                    WUSE[mi * 2 + 0], ia[ni], acc[mi][ni], 0, 0, 0);           \
                acc[mi][ni] = __builtin_amdgcn_mfma_f32_16x16x32_bf16(         \
                    WUSE[mi * 2 + 0], il[ni], acc[mi][ni], 0, 0, 0);           \
                acc[mi][ni] = __builtin_amdgcn_mfma_f32_16x16x32_bf16(         \
                    WUSE[mi * 2 + 1], ia[ni], acc[mi][ni], 0, 0, 0);           \
            }                                                                  \
        }                                                                      \
    }

// one cin-chunk event: stage next chunk, 9 shift-steps, kh rescales, barrier
#define EVENT(CEV, BUF, NB, W0, W1)                                            \
    {                                                                          \
        if ((CEV) < 15) STAGE((CEV) + 1, NB)                                   \
        STEP(0, CEV, W0, W1, BUF) STEP(1, CEV, W1, W0, BUF)                    \
        STEP(2, CEV, W0, W1, BUF)                                              \
        RESCALE(r01)                                                           \
        STEP(3, CEV, W1, W0, BUF) STEP(4, CEV, W0, W1, BUF)                    \
        STEP(5, CEV, W1, W0, BUF)                                              \
        RESCALE(r12)                                                           \
        STEP(6, CEV, W0, W1, BUF) STEP(7, CEV, W1, W0, BUF)                    \
        STEP(8, CEV, W0, W1, BUF)                                              \
        if ((CEV) < 15) RESCALE(r20)                                           \
        __syncthreads();                                                       \
    }

    // prologue: stage chunk 0 into buf0, load W(step s9=0, c=0) = index 0
    STAGE(0, 0)
    #pragma unroll
    for (int j = 0; j < 8; ++j) wA[j] = *(const short8*)(wpBase + j * 512);
    __syncthreads();

    for (int cp = 0; cp < 8; ++cp) {
        EVENT(2 * cp,     0, 1, wA, wB)
        EVENT(2 * cp + 1, 1, 0, wB, wA)
    }
#undef EVENT
#undef STEP
#undef RESCALE
#undef STAGE

    // epilogue: x d2, store (col=lane&15 -> pixel, row=(lane>>4)*4+reg -> cout)
    const int cout_base = coutblk << 7;
    #pragma unroll
    for (int mi = 0; mi < 4; ++mi) {
        const int crow = cout_base + wr + mi * 16 + ((lane >> 4) << 2);
        #pragma unroll
        for (int ni = 0; ni < 4; ++ni) {
            const int ccol = pix_base + wc + ni * 16 + (lane & 15);
            float* op = out + ((size_t)(b << 9) + crow) * 1024 + ccol;
            f32x4 c = acc[mi][ni];
            #pragma unroll
            for (int r = 0; r < 4; ++r)
                op[(size_t)r * 1024] = c[r] * d2;
        }
    }
}

extern "C" void kernel_launch(void* const* d_in, const int* in_sizes, int n_in,
                              void* d_out, int out_size, void* d_ws, size_t ws_size,
                              hipStream_t stream) {
    const float* img  = (const float*)d_in[0];   // [16][512][32][32]
    const float* wl   = (const float*)d_in[1];   // [16][512]
    const float* dk   = (const float*)d_in[2];   // [512][512]
    const float* bias = (const float*)d_in[3];   // [512]
    const float* cw   = (const float*)d_in[4];   // [3][3][512][512]
    float* out = (float*)d_out;

    float* style = (float*)d_ws;                           // 8192 f32
    float* S     = style + 8192;                           // 1536 f32
    float* dn    = S + 1536;                               // 48 f32
    ushort* wt3  = (ushort*)((char*)d_ws + 65536);         // 4*144*8192 elems
    ushort* ihi  = wt3 + (size_t)4 * 144 * 8192;           // [16][34][34][512]
    ushort* ilo  = ihi + (size_t)16 * 34 * 34 * 512;

    hipMemsetAsync(S, 0, 1536 * sizeof(float), stream);
    style_kernel<<<dim3(8, 16), 256, 0, stream>>>(wl, dk, bias, style);
    wsplit_kernel<<<dim3(72, 8), 256, 0, stream>>>(cw, wt3, S);
    denom_kernel<<<48, 64, 0, stream>>>(S, style, dn);
    isplit_kernel<<<dim3(34, 16), 256, 0, stream>>>(img, style, ihi, ilo);

    conv_gemm<<<512, 256, 0, stream>>>(wt3, ihi, ilo, dn, out);
}